// Round 5
// baseline (40.650 us; speedup 1.0000x reference)
//
#include <hip/hip_runtime.h>
#include <stdint.h>

#define S_TOK 8192
#define D_DIM 768
#define B_SZ  4
#define K_TOP 512
#define NSLICE 32
#define SLICE (S_TOK / NSLICE)  // 256

// ---------------- Kernel 1: importance[s] = 0.25 * sum_b ||h[b,s,:]|| ----------------
// One block per token, one wave per batch row. Each wave: 3 float4 loads (3 KB
// contiguous), FMA, 6-step butterfly, LDS write. Thread 0 combines 4 partials.
// Short streaming waves, tiny VGPR footprint -> max occupancy, fast turnover.
__global__ __launch_bounds__(256) void importance_kernel(const float4* __restrict__ h4,
                                                         uint32_t* __restrict__ imp_u) {
    const int D4 = D_DIM / 4;        // 192
    const int s = blockIdx.x;        // token
    const int b = threadIdx.x >> 6;  // batch = wave id (4 waves)
    const int lane = threadIdx.x & 63;
    __shared__ float s_red[B_SZ];

    const float4* row = h4 + ((size_t)b * S_TOK + (size_t)s) * D4;
    float4 v0 = row[lane];
    float4 v1 = row[lane + 64];
    float4 v2 = row[lane + 128];
    float ss = 0.f;
    ss += v0.x * v0.x + v0.y * v0.y + v0.z * v0.z + v0.w * v0.w;
    ss += v1.x * v1.x + v1.y * v1.y + v1.z * v1.z + v1.w * v1.w;
    ss += v2.x * v2.x + v2.y * v2.y + v2.z * v2.z + v2.w * v2.w;
#pragma unroll
    for (int off = 32; off >= 1; off >>= 1) ss += __shfl_xor(ss, off);
    if (lane == 0) s_red[b] = ss;
    __syncthreads();
    if (threadIdx.x == 0) {
        float acc = sqrtf(s_red[0]) + sqrtf(s_red[1]) + sqrtf(s_red[2]) + sqrtf(s_red[3]);
        // norms are >= 0, so float bits compare as uint32 — store bits directly
        imp_u[s] = __float_as_uint(acc * 0.25f);
    }
}

// ---------------- Kernel 2: all-pairs partial rank ----------------
// rank(s) = #{s' : key[s'] > key[s]  ||  (key[s'] == key[s] && s' < s)}.
// Block (grp, c): tokens [grp*256, grp*256+256) vs slice keys [c*256, c*256+256).
// Slice reads are wave-uniform -> scalar loads through K$; no LDS, no atomics.
__global__ __launch_bounds__(256) void rank_kernel(const uint32_t* __restrict__ imp_u,
                                                   uint32_t* __restrict__ partial) {
    const int grp = blockIdx.x >> 5;   // 0..31
    const int c   = blockIdx.x & 31;   // 0..31
    const int s   = grp * 256 + threadIdx.x;
    const uint32_t ks = imp_u[s];
    const uint4* slice4 = (const uint4*)(imp_u + c * SLICE);
    uint32_t cnt = 0;
#pragma unroll 8
    for (int j4 = 0; j4 < SLICE / 4; ++j4) {
        uint4 kv = slice4[j4];                 // uniform -> s_load_dwordx4
        const int jb = c * SLICE + j4 * 4;
        cnt += (kv.x > ks || (kv.x == ks && (jb + 0) < s)) ? 1u : 0u;
        cnt += (kv.y > ks || (kv.y == ks && (jb + 1) < s)) ? 1u : 0u;
        cnt += (kv.z > ks || (kv.z == ks && (jb + 2) < s)) ? 1u : 0u;
        cnt += (kv.w > ks || (kv.w == ks && (jb + 3) < s)) ? 1u : 0u;
    }
    partial[c * S_TOK + s] = cnt;              // coalesced
}

// ---------------- Kernel 3: sum partials -> rank; compact map[rank] = token ----------
// 32 blocks x 256 threads, one thread per token; fully coalesced partial reads.
__global__ __launch_bounds__(256) void summap_kernel(const uint32_t* __restrict__ partial,
                                                     int* __restrict__ map) {
    const int s = blockIdx.x * 256 + threadIdx.x;
    uint32_t r = 0;
#pragma unroll
    for (int c = 0; c < NSLICE; ++c) r += partial[c * S_TOK + s];
    if (r < K_TOP) map[r] = s;  // ranks are a bijection; 512 scattered 4B stores
}

// ---------------- Kernel 4: out[r,:] = 0.25 * sum_b h[b, map[r], :] ----------------
// One block per output row; 192 threads x float4 = 768 floats, coalesced.
__global__ __launch_bounds__(192) void gather_kernel(const float4* __restrict__ h4,
                                                     const int* __restrict__ map,
                                                     float4* __restrict__ out4) {
    const int D4 = D_DIM / 4;  // 192
    const size_t SD4 = (size_t)S_TOK * D4;
    const int idx = map[blockIdx.x];
    const float4* base = h4 + (size_t)idx * D4;
    const int d = threadIdx.x;
    float4 a = base[d];
    float4 b = base[d + SD4];
    float4 c = base[d + 2 * SD4];
    float4 e = base[d + 3 * SD4];
    float4 r;
    r.x = 0.25f * (a.x + b.x + c.x + e.x);
    r.y = 0.25f * (a.y + b.y + c.y + e.y);
    r.z = 0.25f * (a.z + b.z + c.z + e.z);
    r.w = 0.25f * (a.w + b.w + c.w + e.w);
    out4[(size_t)blockIdx.x * D4 + d] = r;
}

extern "C" void kernel_launch(void* const* d_in, const int* in_sizes, int n_in,
                              void* d_out, int out_size, void* d_ws, size_t ws_size,
                              hipStream_t stream) {
    const float* h = (const float*)d_in[0];
    // d_in[1] (memory) is dead: k == MEMORY_SIZE, every row is overwritten.
    float* out = (float*)d_out;
    uint32_t* imp_u = (uint32_t*)d_ws;
    uint32_t* partial = (uint32_t*)((char*)d_ws + S_TOK * sizeof(uint32_t));
    int* map = (int*)((char*)d_ws + S_TOK * sizeof(uint32_t) + NSLICE * S_TOK * sizeof(uint32_t));

    importance_kernel<<<S_TOK, 256, 0, stream>>>((const float4*)h, imp_u);
    rank_kernel<<<NSLICE * (S_TOK / 256), 256, 0, stream>>>(imp_u, partial);
    summap_kernel<<<S_TOK / 256, 256, 0, stream>>>(partial, map);
    gather_kernel<<<K_TOP, 192, 0, stream>>>((const float4*)h, map, (float4*)out);
}

// Round 6
// 40.517 us; speedup vs baseline: 1.0033x; 1.0033x over previous
//
#include <hip/hip_runtime.h>
#include <stdint.h>

#define S_TOK 8192
#define D_DIM 768
#define B_SZ  4
#define K_TOP 512
#define NSLICE 32
#define SLICE (S_TOK / NSLICE)  // 256

// ---------------- Kernel 1: importance[s] = 0.25 * sum_b ||h[b,s,:]|| ----------------
// One wave per token. ALL 12 loads (4 batches x 3) are issued independently before
// any cross-lane op; per-thread accumulation into 4 independent dots (row = j/3 is
// lane-uniform since 192 float4/row = 3 x 64). One butterfly tail per batch at the
// end. Max outstanding loads per wave -> streaming at read-BW ceiling.
__global__ __launch_bounds__(256) void importance_kernel(const float4* __restrict__ h4,
                                                         uint32_t* __restrict__ imp_u) {
    const int D4 = D_DIM / 4;               // 192
    const size_t SB = (size_t)S_TOK * D4;   // batch stride in float4
    const int wave = (blockIdx.x * blockDim.x + threadIdx.x) >> 6;  // token, < 8192
    const int lane = threadIdx.x & 63;
    const float4* r = h4 + (size_t)wave * D4 + lane;

    // 12 independent loads (4 base addresses x immediate offsets 0/1024/2048 B)
    float4 v0 = r[0 * SB + 0],  v1 = r[0 * SB + 64],  v2 = r[0 * SB + 128];
    float4 v3 = r[1 * SB + 0],  v4 = r[1 * SB + 64],  v5 = r[1 * SB + 128];
    float4 v6 = r[2 * SB + 0],  v7 = r[2 * SB + 64],  v8 = r[2 * SB + 128];
    float4 v9 = r[3 * SB + 0],  vA = r[3 * SB + 64],  vB = r[3 * SB + 128];

    float d0 = v0.x * v0.x + v0.y * v0.y + v0.z * v0.z + v0.w * v0.w;
    float d1 = v1.x * v1.x + v1.y * v1.y + v1.z * v1.z + v1.w * v1.w;
    float d2 = v2.x * v2.x + v2.y * v2.y + v2.z * v2.z + v2.w * v2.w;
    float d3 = v3.x * v3.x + v3.y * v3.y + v3.z * v3.z + v3.w * v3.w;
    float d4 = v4.x * v4.x + v4.y * v4.y + v4.z * v4.z + v4.w * v4.w;
    float d5 = v5.x * v5.x + v5.y * v5.y + v5.z * v5.z + v5.w * v5.w;
    float d6 = v6.x * v6.x + v6.y * v6.y + v6.z * v6.z + v6.w * v6.w;
    float d7 = v7.x * v7.x + v7.y * v7.y + v7.z * v7.z + v7.w * v7.w;
    float d8 = v8.x * v8.x + v8.y * v8.y + v8.z * v8.z + v8.w * v8.w;
    float d9 = v9.x * v9.x + v9.y * v9.y + v9.z * v9.z + v9.w * v9.w;
    float dA = vA.x * vA.x + vA.y * vA.y + vA.z * vA.z + vA.w * vA.w;
    float dB = vB.x * vB.x + vB.y * vB.y + vB.z * vB.z + vB.w * vB.w;

    // same per-row FP order as previous rounds: (d_{3b} + d_{3b+1}) + d_{3b+2}
    float a0 = d0 + d1 + d2;
    float a1 = d3 + d4 + d5;
    float a2 = d6 + d7 + d8;
    float a3 = d9 + dA + dB;

    // 4 independent butterfly chains (interleavable by the scheduler)
#pragma unroll
    for (int off = 32; off >= 1; off >>= 1) {
        a0 += __shfl_xor(a0, off);
        a1 += __shfl_xor(a1, off);
        a2 += __shfl_xor(a2, off);
        a3 += __shfl_xor(a3, off);
    }
    if (lane == 0) {
        float acc = sqrtf(a0) + sqrtf(a1) + sqrtf(a2) + sqrtf(a3);
        // norms are >= 0, so float bits compare as uint32 — store bits directly
        imp_u[wave] = __float_as_uint(acc * 0.25f);
    }
}

// ---------------- Kernel 2: all-pairs partial rank ----------------
// rank(s) = #{s' : key[s'] > key[s]  ||  (key[s'] == key[s] && s' < s)}.
// Block (grp, c): tokens [grp*256, grp*256+256) vs slice keys [c*256, c*256+256).
// Slice reads are wave-uniform -> scalar loads through K$; no LDS, no atomics.
__global__ __launch_bounds__(256) void rank_kernel(const uint32_t* __restrict__ imp_u,
                                                   uint32_t* __restrict__ partial) {
    const int grp = blockIdx.x >> 5;   // 0..31
    const int c   = blockIdx.x & 31;   // 0..31
    const int s   = grp * 256 + threadIdx.x;
    const uint32_t ks = imp_u[s];
    const uint4* slice4 = (const uint4*)(imp_u + c * SLICE);
    uint32_t cnt = 0;
#pragma unroll 8
    for (int j4 = 0; j4 < SLICE / 4; ++j4) {
        uint4 kv = slice4[j4];                 // uniform -> s_load_dwordx4
        const int jb = c * SLICE + j4 * 4;
        cnt += (kv.x > ks || (kv.x == ks && (jb + 0) < s)) ? 1u : 0u;
        cnt += (kv.y > ks || (kv.y == ks && (jb + 1) < s)) ? 1u : 0u;
        cnt += (kv.z > ks || (kv.z == ks && (jb + 2) < s)) ? 1u : 0u;
        cnt += (kv.w > ks || (kv.w == ks && (jb + 3) < s)) ? 1u : 0u;
    }
    partial[c * S_TOK + s] = cnt;              // coalesced
}

// ---------------- Kernel 3: sum partials -> rank; compact map[rank] = token ----------
// 32 blocks x 256 threads, one thread per token; fully coalesced partial reads.
__global__ __launch_bounds__(256) void summap_kernel(const uint32_t* __restrict__ partial,
                                                     int* __restrict__ map) {
    const int s = blockIdx.x * 256 + threadIdx.x;
    uint32_t r = 0;
#pragma unroll
    for (int c = 0; c < NSLICE; ++c) r += partial[c * S_TOK + s];
    if (r < K_TOP) map[r] = s;  // ranks are a bijection; 512 scattered 4B stores
}

// ---------------- Kernel 4: out[r,:] = 0.25 * sum_b h[b, map[r], :] ----------------
// One block per output row; 192 threads x float4 = 768 floats, coalesced.
__global__ __launch_bounds__(192) void gather_kernel(const float4* __restrict__ h4,
                                                     const int* __restrict__ map,
                                                     float4* __restrict__ out4) {
    const int D4 = D_DIM / 4;  // 192
    const size_t SD4 = (size_t)S_TOK * D4;
    const int idx = map[blockIdx.x];
    const float4* base = h4 + (size_t)idx * D4;
    const int d = threadIdx.x;
    float4 a = base[d];
    float4 b = base[d + SD4];
    float4 c = base[d + 2 * SD4];
    float4 e = base[d + 3 * SD4];
    float4 r;
    r.x = 0.25f * (a.x + b.x + c.x + e.x);
    r.y = 0.25f * (a.y + b.y + c.y + e.y);
    r.z = 0.25f * (a.z + b.z + c.z + e.z);
    r.w = 0.25f * (a.w + b.w + c.w + e.w);
    out4[(size_t)blockIdx.x * D4 + d] = r;
}

extern "C" void kernel_launch(void* const* d_in, const int* in_sizes, int n_in,
                              void* d_out, int out_size, void* d_ws, size_t ws_size,
                              hipStream_t stream) {
    const float* h = (const float*)d_in[0];
    // d_in[1] (memory) is dead: k == MEMORY_SIZE, every row is overwritten.
    float* out = (float*)d_out;
    uint32_t* imp_u = (uint32_t*)d_ws;
    uint32_t* partial = (uint32_t*)((char*)d_ws + S_TOK * sizeof(uint32_t));
    int* map = (int*)((char*)d_ws + S_TOK * sizeof(uint32_t) + NSLICE * S_TOK * sizeof(uint32_t));

    importance_kernel<<<S_TOK / 4, 256, 0, stream>>>((const float4*)h, imp_u);
    rank_kernel<<<NSLICE * (S_TOK / 256), 256, 0, stream>>>(imp_u, partial);
    summap_kernel<<<S_TOK / 256, 256, 0, stream>>>(partial, map);
    gather_kernel<<<K_TOP, 192, 0, stream>>>((const float4*)h, map, (float4*)out);
}